// Round 1
// baseline (559.088 us; speedup 1.0000x reference)
//
#include <hip/hip_runtime.h>
#include <math.h>

#define NC 8192
#define NF 16384
#define NT 24576
#define NS 32768
#define LASTD 1e-4f
#define PI_F 3.14159265358979323846f

// ws layout (float offsets)
#define WS_CONST 0
#define WS_TFINE 64
#define WS_SIGCO (WS_TFINE + NF)
#define WS_COLCO (WS_SIGCO + NC)
#define WS_SIGFI (WS_COLCO + 3*NC)
#define WS_COLFI (WS_SIGFI + NF)
#define WS_SORT  (WS_COLFI + 3*NF)

// ---------------- prep: fold dir encoding into color bias, point affine ----------------
__global__ void k_prep(const float* hor_, const float* ver_, const float* tm,
                       const float* near_, const float* far_,
                       const float* Wcol, const float* bcol, float* cst) {
  if (threadIdx.x != 0) return;
  float hor = hor_[0], ver = ver_[0], nearv = near_[0], farv = far_[0];
  // reference: reference() negates ver, _render negates again -> d_cam = [hor, ver, 1, 1]
  float dw[3];
  for (int j = 0; j < 3; ++j)
    dw[j] = tm[j*4+0]*hor + tm[j*4+1]*ver + tm[j*4+2] + tm[j*4+3];
  float enc[24];
  for (int i = 0; i < 3; ++i)
    for (int l = 0; l < 4; ++l) {
      float f = PI_F * exp2f(2.f*(float)l);
      float ang = dw[i]*f;
      enc[i*8 + l*2]     = sinf(ang);
      enc[i*8 + l*2 + 1] = cosf(ang);
    }
  for (int c = 0; c < 3; ++c) {
    float s = bcol[c];
    for (int d = 0; d < 24; ++d) s += enc[d]*Wcol[d*3+c];
    cst[6+c] = s;   // effective color bias
  }
  for (int j = 0; j < 3; ++j) {
    cst[0+j] = tm[j*4+0]*hor + tm[j*4+1]*ver + tm[j*4+3]; // a
    cst[3+j] = tm[j*4+2];                                  // b  (pts_wrd = a + b*t)
  }
  cst[9]  = nearv;
  cst[10] = (farv - nearv) / (float)(NC - 1); // linspace step (dt)
  cst[11] = (farv - nearv) / (float)NC;       // delta_co
}

// ---------------- MLP: 32 points/block, fp32, LDS h + double-buffered W slices ----------------
__global__ __launch_bounds__(256) void k_mlp(
    const float* __restrict__ cst,
    const float* __restrict__ W0, const float* __restrict__ b0,
    const float* __restrict__ Wh, const float* __restrict__ bh,
    const float* __restrict__ Wsig, const float* __restrict__ bsig,
    const float* __restrict__ Wcol,
    const float* __restrict__ tf, int npts,
    float* __restrict__ sig_out, float* __restrict__ col_out)
{
  __shared__ float h[32][256];       // 32 KB
  __shared__ float wbuf[2][2048];    // 16 KB (8 k-rows x 256)
  const int tid = threadIdx.x;
  const int mg = tid >> 6;           // 0..3  (wave id)
  const int ng = tid & 63;           // lane
  const int p0 = blockIdx.x * 32;

  // ---- positional encoding into h[p][0..59], zeros 60..63 ----
  {
    float a0=cst[0],a1=cst[1],a2=cst[2];
    float bb0=cst[3],bb1=cst[4],bb2=cst[5];
    float nearv=cst[9], step=cst[10];
    for (int idx = tid; idx < 32*64; idx += 256) {
      int p = idx >> 6, d = idx & 63;
      float val = 0.f;
      if (d < 60) {
        int gp = p0 + p;
        float t = tf ? tf[gp] : fmaf(step, (float)gp, nearv);
        int i3 = d/20, rem = d%20, l = rem>>1;
        float x = (i3==0) ? fmaf(bb0,t,a0) : (i3==1) ? fmaf(bb1,t,a1) : fmaf(bb2,t,a2);
        float ang = x * (PI_F * exp2f(2.f*(float)l));
        val = (rem & 1) ? cosf(ang) : sinf(ang);
      }
      h[p][d] = val;
    }
  }
  __syncthreads();

  const float* W = W0; const float* bias = b0;
  int Kl = 64, Klim = 60*256;
  float acc[8][4];

  for (int l = 0; l < 9; ++l) {
    const bool relu = (l < 8);
    #pragma unroll
    for (int i = 0; i < 8; ++i)
      #pragma unroll
      for (int c = 0; c < 4; ++c) acc[i][c] = 0.f;

    const int nchunk = Kl >> 3;
    // stage chunk 0
    {
      int f0 = tid*4, f1 = 1024 + tid*4;
      float4 v0 = make_float4(0,0,0,0), v1 = make_float4(0,0,0,0);
      if (f0 < Klim) v0 = *(const float4*)&W[f0];
      if (f1 < Klim) v1 = *(const float4*)&W[f1];
      *(float4*)&wbuf[0][tid*4] = v0;
      *(float4*)&wbuf[0][1024 + tid*4] = v1;
    }
    __syncthreads();

    for (int c = 0; c < nchunk; ++c) {
      float4 n0 = make_float4(0,0,0,0), n1 = make_float4(0,0,0,0);
      if (c+1 < nchunk) {
        int f0 = (c+1)*2048 + tid*4, f1 = f0 + 1024;
        if (f0 < Klim) n0 = *(const float4*)&W[f0];
        if (f1 < Klim) n1 = *(const float4*)&W[f1];
      }
      const float* wb = wbuf[c & 1];
      #pragma unroll
      for (int k4 = 0; k4 < 2; ++k4) {
        float4 wv[4];
        #pragma unroll
        for (int kk = 0; kk < 4; ++kk)
          wv[kk] = *(const float4*)&wb[(k4*4+kk)*256 + ng*4];
        #pragma unroll
        for (int i = 0; i < 8; ++i) {
          float4 hv = *(const float4*)&h[mg*8+i][c*8 + k4*4]; // same addr whole wave: broadcast
          acc[i][0] = fmaf(hv.x, wv[0].x, acc[i][0]);
          acc[i][1] = fmaf(hv.x, wv[0].y, acc[i][1]);
          acc[i][2] = fmaf(hv.x, wv[0].z, acc[i][2]);
          acc[i][3] = fmaf(hv.x, wv[0].w, acc[i][3]);
          acc[i][0] = fmaf(hv.y, wv[1].x, acc[i][0]);
          acc[i][1] = fmaf(hv.y, wv[1].y, acc[i][1]);
          acc[i][2] = fmaf(hv.y, wv[1].z, acc[i][2]);
          acc[i][3] = fmaf(hv.y, wv[1].w, acc[i][3]);
          acc[i][0] = fmaf(hv.z, wv[2].x, acc[i][0]);
          acc[i][1] = fmaf(hv.z, wv[2].y, acc[i][1]);
          acc[i][2] = fmaf(hv.z, wv[2].z, acc[i][2]);
          acc[i][3] = fmaf(hv.z, wv[2].w, acc[i][3]);
          acc[i][0] = fmaf(hv.w, wv[3].x, acc[i][0]);
          acc[i][1] = fmaf(hv.w, wv[3].y, acc[i][1]);
          acc[i][2] = fmaf(hv.w, wv[3].z, acc[i][2]);
          acc[i][3] = fmaf(hv.w, wv[3].w, acc[i][3]);
        }
      }
      if (c+1 < nchunk) {
        *(float4*)&wbuf[(c+1)&1][tid*4] = n0;
        *(float4*)&wbuf[(c+1)&1][1024 + tid*4] = n1;
      }
      __syncthreads();
    }

    // bias + activation + write back h
    float4 bv = *(const float4*)&bias[ng*4];
    #pragma unroll
    for (int i = 0; i < 8; ++i) {
      float o0 = acc[i][0]+bv.x, o1 = acc[i][1]+bv.y, o2 = acc[i][2]+bv.z, o3 = acc[i][3]+bv.w;
      if (relu) { o0=fmaxf(o0,0.f); o1=fmaxf(o1,0.f); o2=fmaxf(o2,0.f); o3=fmaxf(o3,0.f); }
      *(float4*)&h[mg*8+i][ng*4] = make_float4(o0,o1,o2,o3);
    }
    __syncthreads();

    W = Wh + l*65536; bias = bh + l*256; Kl = 256; Klim = 65536;
  }

  // ---- heads: sigma + color (dirs folded into cst[6..8]) ----
  const int p = tid >> 3, s = tid & 7;
  float sacc = 0.f;
  for (int k = s*32; k < s*32+32; ++k) sacc += h[p][k]*Wsig[k];
  sacc += __shfl_xor(sacc, 1); sacc += __shfl_xor(sacc, 2); sacc += __shfl_xor(sacc, 4);
  if (s == 0) {
    float z = sacc + bsig[0];
    sig_out[p0+p] = 1.f/(1.f+expf(-z));
  }
  const float* Wc = Wcol + 72;  // rows 24..279
  for (int cch = 0; cch < 3; ++cch) {
    float ca = 0.f;
    for (int k = s*32; k < s*32+32; ++k) ca += h[p][k]*Wc[k*3+cch];
    ca += __shfl_xor(ca, 1); ca += __shfl_xor(ca, 2); ca += __shfl_xor(ca, 4);
    if (s == 0) {
      float z = ca + cst[6+cch];
      col_out[cch*npts + p0 + p] = 1.f/(1.f+expf(-z));
    }
  }
}

// ---------------- coarse post: cdf scan, C_coarse, inverse-CDF t_fine ----------------
__global__ __launch_bounds__(1024) void k_postco(
    const float* __restrict__ sigco, const float* __restrict__ colco,
    const float* __restrict__ cst, float* __restrict__ tfine, float* __restrict__ outv)
{
  __shared__ float cdf[NC];
  __shared__ float ts[1024];
  __shared__ float r0[16], r1[16], r2[16];
  const int tid = threadIdx.x;
  float v[8], inc[8];
  float run = 0.f;
  #pragma unroll
  for (int j = 0; j < 8; ++j) { v[j] = sigco[tid*8+j]; run += v[j]; inc[j] = run; }
  ts[tid] = run;
  __syncthreads();
  for (int off = 1; off < 1024; off <<= 1) {
    float x = (tid >= off) ? ts[tid-off] : 0.f;
    __syncthreads();
    ts[tid] += x;
    __syncthreads();
  }
  float excl = ts[tid] - run;
  #pragma unroll
  for (int j = 0; j < 8; ++j) cdf[tid*8+j] = excl + inc[j];
  __syncthreads();

  // C_coarse
  float dco = cst[11];
  float a0=0.f, a1=0.f, a2=0.f;
  #pragma unroll
  for (int j = 0; j < 8; ++j) {
    int i = tid*8+j;
    float T = expf(-dco*(excl+inc[j]));
    float w = T*(1.f-expf(-dco*v[j]));
    a0 += colco[i]*w; a1 += colco[NC+i]*w; a2 += colco[2*NC+i]*w;
  }
  for (int off = 32; off; off >>= 1) {
    a0 += __shfl_down(a0, off); a1 += __shfl_down(a1, off); a2 += __shfl_down(a2, off);
  }
  int wid = tid>>6, lane = tid&63;
  if (lane==0) { r0[wid]=a0; r1[wid]=a1; r2[wid]=a2; }
  __syncthreads();
  if (tid==0) {
    float s0=0,s1=0,s2=0;
    for (int i=0;i<16;++i){s0+=r0[i];s1+=r1[i];s2+=r2[i];}
    outv[0]=s0; outv[1]=s1; outv[2]=s2;
  }

  // t_fine via inverse CDF
  float cdf0 = cdf[0], cdfN = cdf[NC-1];
  float stepi = (cdfN - cdf0) / (float)(NF+1);
  float nearv = cst[9], dt = cst[10];
  for (int r = 0; r < NF/1024; ++r) {
    int j = tid + r*1024;
    float tv = cdf0 + (float)(j+1)*stepi;
    int lo = 0, hi = NC;
    while (lo < hi) { int mid = (lo+hi)>>1; if (cdf[mid] < tv) lo = mid+1; else hi = mid; }
    int idx = lo-1; idx = idx < 0 ? 0 : (idx > NC-2 ? NC-2 : idx);
    float sig1 = sigco[idx+1];
    tfine[j] = fmaf(dt, (float)idx, nearv) + (tv - cdf[idx]) * (dt / sig1);
  }
}

// ---------------- sort fill: 5 rows of NS, +inf padded ----------------
__global__ void k_fill(const float* __restrict__ cst,
                       const float* __restrict__ sigco, const float* __restrict__ colco,
                       const float* __restrict__ sigfi, const float* __restrict__ colfi,
                       const float* __restrict__ tfine, float* __restrict__ srt)
{
  int gid = blockIdx.x*1024 + threadIdx.x;
  int a = gid >> 15, i = gid & (NS-1);
  float v;
  if (a == 0) {
    v = (i < NC) ? fmaf(cst[10], (float)i, cst[9]) : (i < NT ? tfine[i-NC] : INFINITY);
  } else if (a < 4) {
    int c = a-1;
    v = (i < NC) ? colco[c*NC+i] : (i < NT ? colfi[c*NF + (i-NC)] : INFINITY);
  } else {
    v = (i < NC) ? sigco[i] : (i < NT ? sigfi[i-NC] : INFINITY);
  }
  srt[a*NS + i] = v;
}

// ---------------- bitonic sort: local full (k=2..2048) ----------------
__global__ __launch_bounds__(1024) void k_sort_local_full(float* __restrict__ srt)
{
  __shared__ float s[2048];
  int b = blockIdx.x, a = b>>4, seg = b&15;
  float* g = srt + a*NS + seg*2048;
  int t = threadIdx.x;
  s[t] = g[t]; s[t+1024] = g[t+1024];
  __syncthreads();
  int gbase = seg*2048;
  for (int k = 2; k <= 2048; k <<= 1) {
    for (int j = k>>1; j > 0; j >>= 1) {
      int i = ((t & ~(j-1)) << 1) | (t & (j-1));
      int l2 = i | j;
      bool up = (((gbase + i) & k) == 0);
      float x = s[i], y = s[l2];
      bool sw = up ? (x > y) : (x < y);
      if (sw) { s[i] = y; s[l2] = x; }
      __syncthreads();
    }
  }
  g[t] = s[t]; g[t+1024] = s[t+1024];
}

// ---------------- bitonic: one global (k,j) pass, j>=2048 ----------------
__global__ __launch_bounds__(1024) void k_sort_global(float* __restrict__ srt, int k, int j)
{
  int gid = blockIdx.x*1024 + threadIdx.x;  // 5*16384 threads
  int a = gid >> 14;
  int r = gid & 16383;
  int i = ((r & ~(j-1)) << 1) | (r & (j-1));
  int l2 = i | j;
  float* g = srt + a*NS;
  bool up = ((i & k) == 0);
  float x = g[i], y = g[l2];
  bool sw = up ? (x > y) : (x < y);
  if (sw) { g[i] = y; g[l2] = x; }
}

// ---------------- bitonic: local tail (j=1024..1) for stage k ----------------
__global__ __launch_bounds__(1024) void k_sort_local_tail(float* __restrict__ srt, int k)
{
  __shared__ float s[2048];
  int b = blockIdx.x, a = b>>4, seg = b&15;
  float* g = srt + a*NS + seg*2048;
  int t = threadIdx.x;
  s[t] = g[t]; s[t+1024] = g[t+1024];
  __syncthreads();
  int gbase = seg*2048;
  for (int j = 1024; j > 0; j >>= 1) {
    int i = ((t & ~(j-1)) << 1) | (t & (j-1));
    int l2 = i | j;
    bool up = (((gbase + i) & k) == 0);
    float x = s[i], y = s[l2];
    bool sw = up ? (x > y) : (x < y);
    if (sw) { s[i] = y; s[l2] = x; }
    __syncthreads();
  }
  g[t] = s[t]; g[t+1024] = s[t+1024];
}

// ---------------- final: weighted cumsum over sorted bundle ----------------
__global__ __launch_bounds__(1024) void k_final(
    const float* __restrict__ srt, float* __restrict__ outv)
{
  const float* trow = srt;
  const float* c0r = srt + NS;
  const float* c1r = srt + 2*NS;
  const float* c2r = srt + 3*NS;
  const float* sgr = srt + 4*NS;
  __shared__ float ts[1024];
  __shared__ float r0[16], r1[16], r2[16];
  const int tid = threadIdx.x;
  float sd[24], inc[24];
  float run = 0.f;
  int base = tid*24;
  float tprev = trow[base];
  #pragma unroll
  for (int j = 0; j < 24; ++j) {
    int i = base + j;
    float tnext = (i < NT-1) ? trow[i+1] : 0.f;
    float delta = (i == NT-1) ? LASTD : (tnext - tprev);
    sd[j] = delta * sgr[i];
    run += sd[j];
    inc[j] = run;
    tprev = tnext;
  }
  ts[tid] = run; __syncthreads();
  for (int off = 1; off < 1024; off <<= 1) {
    float x = (tid>=off) ? ts[tid-off] : 0.f;
    __syncthreads();
    ts[tid] += x;
    __syncthreads();
  }
  float excl = ts[tid] - run;
  float a0=0.f, a1=0.f, a2=0.f;
  #pragma unroll
  for (int j = 0; j < 24; ++j) {
    int i = base + j;
    float T = expf(-(excl+inc[j]));
    float w = T*(1.f-expf(-sd[j]));
    a0 += c0r[i]*w; a1 += c1r[i]*w; a2 += c2r[i]*w;
  }
  for (int off = 32; off; off >>= 1) {
    a0 += __shfl_down(a0, off); a1 += __shfl_down(a1, off); a2 += __shfl_down(a2, off);
  }
  int wid = tid>>6, lane = tid&63;
  if (lane==0) { r0[wid]=a0; r1[wid]=a1; r2[wid]=a2; }
  __syncthreads();
  if (tid==0) {
    float s0=0,s1=0,s2=0;
    for (int i=0;i<16;++i){s0+=r0[i];s1+=r1[i];s2+=r2[i];}
    outv[3]=s0; outv[4]=s1; outv[5]=s2;
  }
}

extern "C" void kernel_launch(void* const* d_in, const int* in_sizes, int n_in,
                              void* d_out, int out_size, void* d_ws, size_t ws_size,
                              hipStream_t stream) {
  (void)in_sizes; (void)n_in; (void)out_size; (void)ws_size;
  const float* hor  = (const float*)d_in[0];
  const float* ver  = (const float*)d_in[1];
  const float* tm   = (const float*)d_in[2];
  const float* nearp= (const float*)d_in[3];
  const float* farp = (const float*)d_in[4];
  const float* W0   = (const float*)d_in[5];
  const float* b0   = (const float*)d_in[6];
  const float* Wh   = (const float*)d_in[7];
  const float* bh   = (const float*)d_in[8];
  const float* Wsig = (const float*)d_in[9];
  const float* bsig = (const float*)d_in[10];
  const float* Wcol = (const float*)d_in[11];
  const float* bcol = (const float*)d_in[12];
  float* out = (float*)d_out;
  float* ws  = (float*)d_ws;

  float* cst   = ws + WS_CONST;
  float* tfine = ws + WS_TFINE;
  float* sigco = ws + WS_SIGCO;
  float* colco = ws + WS_COLCO;
  float* sigfi = ws + WS_SIGFI;
  float* colfi = ws + WS_COLFI;
  float* srt   = ws + WS_SORT;

  hipLaunchKernelGGL(k_prep, dim3(1), dim3(64), 0, stream,
                     hor, ver, tm, nearp, farp, Wcol, bcol, cst);
  hipLaunchKernelGGL(k_mlp, dim3(NC/32), dim3(256), 0, stream,
                     cst, W0, b0, Wh, bh, Wsig, bsig, Wcol,
                     (const float*)nullptr, NC, sigco, colco);
  hipLaunchKernelGGL(k_postco, dim3(1), dim3(1024), 0, stream,
                     sigco, colco, cst, tfine, out);
  hipLaunchKernelGGL(k_mlp, dim3(NF/32), dim3(256), 0, stream,
                     cst, W0, b0, Wh, bh, Wsig, bsig, Wcol,
                     (const float*)tfine, NF, sigfi, colfi);
  hipLaunchKernelGGL(k_fill, dim3(160), dim3(1024), 0, stream,
                     cst, sigco, colco, sigfi, colfi, tfine, srt);
  hipLaunchKernelGGL(k_sort_local_full, dim3(80), dim3(1024), 0, stream, srt);
  for (int k = 4096; k <= NS; k <<= 1) {
    for (int j = k>>1; j >= 2048; j >>= 1)
      hipLaunchKernelGGL(k_sort_global, dim3(80), dim3(1024), 0, stream, srt, k, j);
    hipLaunchKernelGGL(k_sort_local_tail, dim3(80), dim3(1024), 0, stream, srt, k);
  }
  hipLaunchKernelGGL(k_final, dim3(1), dim3(1024), 0, stream, srt, out);
}

// Round 2
// 218.182 us; speedup vs baseline: 2.5625x; 2.5625x over previous
//
#include <hip/hip_runtime.h>
#include <math.h>

#define NC 8192
#define NF 16384
#define NT 24576
#define NS 32768
#define LASTD 1e-4f
#define PI_F 3.14159265358979323846f

// ws layout (float offsets)
#define WS_CONST 0
#define WS_TFINE 64
#define WS_SIGCO (WS_TFINE + NF)
#define WS_COLCO (WS_SIGCO + NC)
#define WS_SIGFI (WS_COLCO + 3*NC)
#define WS_COLFI (WS_SIGFI + NF)
#define WS_SORT  (WS_COLFI + 3*NF)
#define WS_WT    (WS_SORT + 5*NS)   // bf16 weights, 66 chunks * 8192 ushort

typedef __attribute__((ext_vector_type(8))) short bf16x8;
typedef __attribute__((ext_vector_type(4))) float f32x4;

static __device__ inline unsigned short f2b(float x){
  union { float f; unsigned int u; } c; c.f = x;
  unsigned int u = c.u;
  return (unsigned short)((u + 0x7fffu + ((u>>16)&1u)) >> 16);
}
static __device__ inline float b2f(unsigned short u){
  union { unsigned int u; float f; } c; c.u = ((unsigned int)u)<<16; return c.f;
}

// ---------------- prep: fold dir encoding into color bias, point affine ----------------
__global__ void k_prep(const float* hor_, const float* ver_, const float* tm,
                       const float* near_, const float* far_,
                       const float* Wcol, const float* bcol, float* cst) {
  if (threadIdx.x != 0) return;
  float hor = hor_[0], ver = ver_[0], nearv = near_[0], farv = far_[0];
  float dw[3];
  for (int j = 0; j < 3; ++j)
    dw[j] = tm[j*4+0]*hor + tm[j*4+1]*ver + tm[j*4+2] + tm[j*4+3];
  float enc[24];
  for (int i = 0; i < 3; ++i)
    for (int l = 0; l < 4; ++l) {
      float f = PI_F * exp2f(2.f*(float)l);
      float ang = dw[i]*f;
      enc[i*8 + l*2]     = sinf(ang);
      enc[i*8 + l*2 + 1] = cosf(ang);
    }
  for (int c = 0; c < 3; ++c) {
    float s = bcol[c];
    for (int d = 0; d < 24; ++d) s += enc[d]*Wcol[d*3+c];
    cst[6+c] = s;
  }
  for (int j = 0; j < 3; ++j) {
    cst[0+j] = tm[j*4+0]*hor + tm[j*4+1]*ver + tm[j*4+3];
    cst[3+j] = tm[j*4+2];
  }
  cst[9]  = nearv;
  cst[10] = (farv - nearv) / (float)(NC - 1);
  cst[11] = (farv - nearv) / (float)NC;
}

// ---------------- prep: weights -> bf16 in A-fragment-linear chunk order ----------------
// layout: chunk c (0..65) -> [mt(16)][lane(64)][j(8)] ushort; chunk = 8192 ushort = 16KB
// c<2: layer0 (W0, k = c*32 + (lane>>4)*8 + j, zero-pad k>=60); else layer m=(c-2)>>3, kc=(c-2)&7
__global__ __launch_bounds__(256) void k_prep_w(
    const float* __restrict__ W0, const float* __restrict__ Wh,
    unsigned short* __restrict__ Wt)
{
  int base = (blockIdx.x*256 + threadIdx.x)*4;
  for (int e = base; e < base+4; ++e) {
    int c = e >> 13;
    int r = e & 8191;
    int mt = r >> 9;
    int q = r & 511;
    int ln = q >> 3, j = q & 7;
    int out = mt*16 + (ln & 15);
    int kk = (ln >> 4)*8 + j;
    float v;
    if (c < 2) {
      int k = c*32 + kk;
      v = (k < 60) ? W0[k*256 + out] : 0.f;
    } else {
      int m = (c-2) >> 3, kc = (c-2) & 7;
      v = Wh[m*65536 + (kc*32+kk)*256 + out];
    }
    Wt[e] = f2b(v);
  }
}

// ---------------- MFMA MLP: 32 points/block, 4 waves, bf16 16x16x32 ----------------
// wave w: M-tiles {4w..4w+3} (outputs), N-tiles {0,1} (points). acc[4][2] f32x4.
// hbuf: [32 pts][256] bf16, 16B-slot XOR swizzle (slot ^ (p&7)) for conflict-free B-frag reads.
__global__ __launch_bounds__(256) void k_mlp_mfma(
    const float* __restrict__ cst, const unsigned short* __restrict__ Wt,
    const float* __restrict__ b0, const float* __restrict__ bh,
    const float* __restrict__ Wsig, const float* __restrict__ bsig,
    const float* __restrict__ Wcol,
    const float* __restrict__ tf, int npts,
    float* __restrict__ sig_out, float* __restrict__ col_out)
{
  __shared__ __align__(16) unsigned short hbuf[32*256];   // 16 KB
  __shared__ __align__(16) unsigned short wbuf[2][8192];  // 2 x 16 KB
  const int tid = threadIdx.x;
  const int w = tid >> 6, lane = tid & 63;
  const int lo = lane & 15, hi = lane >> 4;
  const int p0 = blockIdx.x * 32;

  // ---- positional encoding -> hbuf (bf16, swizzled); cols 60..63 zero ----
  {
    float a0=cst[0],a1=cst[1],a2=cst[2];
    float bb0=cst[3],bb1=cst[4],bb2=cst[5];
    float nearv=cst[9], step=cst[10];
    for (int idx = tid; idx < 32*64; idx += 256) {
      int p = idx >> 6, d = idx & 63;
      unsigned short val = 0;
      if (d < 60) {
        int gp = p0 + p;
        float t = tf ? tf[gp] : fmaf(step, (float)gp, nearv);
        int i3 = d/20, rem = d%20, l = rem>>1;
        float x = (i3==0)? fmaf(bb0,t,a0) : (i3==1)? fmaf(bb1,t,a1) : fmaf(bb2,t,a2);
        float ang = x * (PI_F * exp2f(2.f*(float)l));
        val = f2b((rem&1)? cosf(ang) : sinf(ang));
      }
      hbuf[p*256 + (((d>>3)^(p&7))<<3) + (d&7)] = val;
    }
  }
  __syncthreads();

  f32x4 acc[4][2];
  for (int l = 0; l < 9; ++l) {
    const int nchunk = (l==0)? 2 : 8;
    const unsigned short* wl = Wt + (size_t)((l==0)? 0 : (2 + (l-1)*8)) * 8192;
    const f32x4 z4 = {0.f,0.f,0.f,0.f};
    #pragma unroll
    for (int mi=0;mi<4;++mi) { acc[mi][0]=z4; acc[mi][1]=z4; }

    // stage chunk 0 (wave-uniform LDS base + lane*16 implicit)
    {
      const char* s = (const char*)wl + w*4096 + lane*16;
      char* dbase = (char*)&wbuf[0][0] + w*4096;
      #pragma unroll
      for (int i=0;i<4;++i)
        __builtin_amdgcn_global_load_lds(
           (const __attribute__((address_space(1))) unsigned int*)(s + i*1024),
           (__attribute__((address_space(3))) unsigned int*)(dbase + i*1024), 16, 0, 0);
    }
    __syncthreads();

    for (int kc = 0; kc < nchunk; ++kc) {
      if (kc+1 < nchunk) {
        const char* s = (const char*)wl + (kc+1)*16384 + w*4096 + lane*16;
        char* dbase = (char*)&wbuf[(kc+1)&1][0] + w*4096;
        #pragma unroll
        for (int i=0;i<4;++i)
          __builtin_amdgcn_global_load_lds(
             (const __attribute__((address_space(1))) unsigned int*)(s + i*1024),
             (__attribute__((address_space(3))) unsigned int*)(dbase + i*1024), 16, 0, 0);
      }
      const unsigned short* wb = &wbuf[kc&1][0];
      bf16x8 afr[4], bfr[2];
      #pragma unroll
      for (int mi=0;mi<4;++mi)
        afr[mi] = *(const bf16x8*)&wb[((w*4+mi)*64 + lane)*8];
      #pragma unroll
      for (int ni=0;ni<2;++ni) {
        int p = ni*16 + lo;
        int slot = kc*4 + hi;
        bfr[ni] = *(const bf16x8*)&hbuf[p*256 + (((slot^(p&7)))<<3)];
      }
      #pragma unroll
      for (int mi=0;mi<4;++mi)
        #pragma unroll
        for (int ni=0;ni<2;++ni)
          acc[mi][ni] = __builtin_amdgcn_mfma_f32_16x16x32_bf16(afr[mi], bfr[ni], acc[mi][ni], 0, 0, 0);
      __syncthreads();   // staged chunk ready (compiler drains vmcnt), wbuf swap safe
    }

    // epilogue: bias + relu, pack 4 consecutive outs -> ds_write_b64 (swizzled)
    const float* bias = (l==0)? b0 : bh + (l-1)*256;
    const bool relu = (l < 8);
    #pragma unroll
    for (int mi=0;mi<4;++mi) {
      int mt = w*4+mi;
      f32x4 bv = *(const f32x4*)&bias[mt*16 + hi*4];
      #pragma unroll
      for (int ni=0;ni<2;++ni) {
        f32x4 v = acc[mi][ni];
        float o0=v[0]+bv[0], o1=v[1]+bv[1], o2=v[2]+bv[2], o3=v[3]+bv[3];
        if (relu){o0=fmaxf(o0,0.f);o1=fmaxf(o1,0.f);o2=fmaxf(o2,0.f);o3=fmaxf(o3,0.f);}
        int p = ni*16 + lo;
        int colu = mt*16 + hi*4;
        int slot = colu >> 3, off = colu & 7;
        ushort4 uv = make_ushort4(f2b(o0), f2b(o1), f2b(o2), f2b(o3));
        *(ushort4*)&hbuf[p*256 + ((slot^(p&7))<<3) + off] = uv;
      }
    }
    // next layer's post-stage __syncthreads orders these writes before reads
  }
  __syncthreads();

  // ---- heads: 4 threads per point, 64 k each; fp32 head weights ----
  if (tid < 128) {
    int p = tid >> 2, s = tid & 3;
    float as_=0.f, a0=0.f, a1=0.f, a2=0.f;
    for (int q=0;q<8;++q) {
      int slot = s*8+q;
      bf16x8 hv = *(const bf16x8*)&hbuf[p*256 + ((slot^(p&7))<<3)];
      #pragma unroll
      for (int j=0;j<8;++j) {
        float hf = b2f((unsigned short)hv[j]);
        int k = s*64 + q*8 + j;
        as_ = fmaf(hf, Wsig[k], as_);
        const float* wc = Wcol + 72 + k*3;
        a0 = fmaf(hf, wc[0], a0);
        a1 = fmaf(hf, wc[1], a1);
        a2 = fmaf(hf, wc[2], a2);
      }
    }
    as_ += __shfl_xor(as_,1); as_ += __shfl_xor(as_,2);
    a0 += __shfl_xor(a0,1); a0 += __shfl_xor(a0,2);
    a1 += __shfl_xor(a1,1); a1 += __shfl_xor(a1,2);
    a2 += __shfl_xor(a2,1); a2 += __shfl_xor(a2,2);
    if (s == 0) {
      sig_out[p0+p] = 1.f/(1.f+expf(-(as_ + bsig[0])));
      col_out[0*npts + p0+p] = 1.f/(1.f+expf(-(a0 + cst[6])));
      col_out[1*npts + p0+p] = 1.f/(1.f+expf(-(a1 + cst[7])));
      col_out[2*npts + p0+p] = 1.f/(1.f+expf(-(a2 + cst[8])));
    }
  }
}

// ---------------- coarse post: cdf scan, C_coarse, inverse-CDF t_fine ----------------
__global__ __launch_bounds__(1024) void k_postco(
    const float* __restrict__ sigco, const float* __restrict__ colco,
    const float* __restrict__ cst, float* __restrict__ tfine, float* __restrict__ outv)
{
  __shared__ float cdf[NC];
  __shared__ float ts[1024];
  __shared__ float r0[16], r1[16], r2[16];
  const int tid = threadIdx.x;
  float v[8], inc[8];
  float run = 0.f;
  #pragma unroll
  for (int j = 0; j < 8; ++j) { v[j] = sigco[tid*8+j]; run += v[j]; inc[j] = run; }
  ts[tid] = run;
  __syncthreads();
  for (int off = 1; off < 1024; off <<= 1) {
    float x = (tid >= off) ? ts[tid-off] : 0.f;
    __syncthreads();
    ts[tid] += x;
    __syncthreads();
  }
  float excl = ts[tid] - run;
  #pragma unroll
  for (int j = 0; j < 8; ++j) cdf[tid*8+j] = excl + inc[j];
  __syncthreads();

  float dco = cst[11];
  float a0=0.f, a1=0.f, a2=0.f;
  #pragma unroll
  for (int j = 0; j < 8; ++j) {
    int i = tid*8+j;
    float T = expf(-dco*(excl+inc[j]));
    float w = T*(1.f-expf(-dco*v[j]));
    a0 += colco[i]*w; a1 += colco[NC+i]*w; a2 += colco[2*NC+i]*w;
  }
  for (int off = 32; off; off >>= 1) {
    a0 += __shfl_down(a0, off); a1 += __shfl_down(a1, off); a2 += __shfl_down(a2, off);
  }
  int wid = tid>>6, lane = tid&63;
  if (lane==0) { r0[wid]=a0; r1[wid]=a1; r2[wid]=a2; }
  __syncthreads();
  if (tid==0) {
    float s0=0,s1=0,s2=0;
    for (int i=0;i<16;++i){s0+=r0[i];s1+=r1[i];s2+=r2[i];}
    outv[0]=s0; outv[1]=s1; outv[2]=s2;
  }

  float cdf0 = cdf[0], cdfN = cdf[NC-1];
  float stepi = (cdfN - cdf0) / (float)(NF+1);
  float nearv = cst[9], dt = cst[10];
  for (int r = 0; r < NF/1024; ++r) {
    int j = tid + r*1024;
    float tv = cdf0 + (float)(j+1)*stepi;
    int lo = 0, hi = NC;
    while (lo < hi) { int mid = (lo+hi)>>1; if (cdf[mid] < tv) lo = mid+1; else hi = mid; }
    int idx = lo-1; idx = idx < 0 ? 0 : (idx > NC-2 ? NC-2 : idx);
    float sig1 = sigco[idx+1];
    tfine[j] = fmaf(dt, (float)idx, nearv) + (tv - cdf[idx]) * (dt / sig1);
  }
}

// ---------------- sort fill: 5 rows of NS, +inf padded ----------------
__global__ void k_fill(const float* __restrict__ cst,
                       const float* __restrict__ sigco, const float* __restrict__ colco,
                       const float* __restrict__ sigfi, const float* __restrict__ colfi,
                       const float* __restrict__ tfine, float* __restrict__ srt)
{
  int gid = blockIdx.x*1024 + threadIdx.x;
  int a = gid >> 15, i = gid & (NS-1);
  float v;
  if (a == 0) {
    v = (i < NC) ? fmaf(cst[10], (float)i, cst[9]) : (i < NT ? tfine[i-NC] : INFINITY);
  } else if (a < 4) {
    int c = a-1;
    v = (i < NC) ? colco[c*NC+i] : (i < NT ? colfi[c*NF + (i-NC)] : INFINITY);
  } else {
    v = (i < NC) ? sigco[i] : (i < NT ? sigfi[i-NC] : INFINITY);
  }
  srt[a*NS + i] = v;
}

// ---------------- bitonic sort: local full (k=2..2048) ----------------
__global__ __launch_bounds__(1024) void k_sort_local_full(float* __restrict__ srt)
{
  __shared__ float s[2048];
  int b = blockIdx.x, a = b>>4, seg = b&15;
  float* g = srt + a*NS + seg*2048;
  int t = threadIdx.x;
  s[t] = g[t]; s[t+1024] = g[t+1024];
  __syncthreads();
  int gbase = seg*2048;
  for (int k = 2; k <= 2048; k <<= 1) {
    for (int j = k>>1; j > 0; j >>= 1) {
      int i = ((t & ~(j-1)) << 1) | (t & (j-1));
      int l2 = i | j;
      bool up = (((gbase + i) & k) == 0);
      float x = s[i], y = s[l2];
      bool sw = up ? (x > y) : (x < y);
      if (sw) { s[i] = y; s[l2] = x; }
      __syncthreads();
    }
  }
  g[t] = s[t]; g[t+1024] = s[t+1024];
}

// ---------------- bitonic: one global (k,j) pass, j>=2048 ----------------
__global__ __launch_bounds__(1024) void k_sort_global(float* __restrict__ srt, int k, int j)
{
  int gid = blockIdx.x*1024 + threadIdx.x;
  int a = gid >> 14;
  int r = gid & 16383;
  int i = ((r & ~(j-1)) << 1) | (r & (j-1));
  int l2 = i | j;
  float* g = srt + a*NS;
  bool up = ((i & k) == 0);
  float x = g[i], y = g[l2];
  bool sw = up ? (x > y) : (x < y);
  if (sw) { g[i] = y; g[l2] = x; }
}

// ---------------- bitonic: local tail (j=1024..1) for stage k ----------------
__global__ __launch_bounds__(1024) void k_sort_local_tail(float* __restrict__ srt, int k)
{
  __shared__ float s[2048];
  int b = blockIdx.x, a = b>>4, seg = b&15;
  float* g = srt + a*NS + seg*2048;
  int t = threadIdx.x;
  s[t] = g[t]; s[t+1024] = g[t+1024];
  __syncthreads();
  int gbase = seg*2048;
  for (int j = 1024; j > 0; j >>= 1) {
    int i = ((t & ~(j-1)) << 1) | (t & (j-1));
    int l2 = i | j;
    bool up = (((gbase + i) & k) == 0);
    float x = s[i], y = s[l2];
    bool sw = up ? (x > y) : (x < y);
    if (sw) { s[i] = y; s[l2] = x; }
    __syncthreads();
  }
  g[t] = s[t]; g[t+1024] = s[t+1024];
}

// ---------------- final: weighted cumsum over sorted bundle ----------------
__global__ __launch_bounds__(1024) void k_final(
    const float* __restrict__ srt, float* __restrict__ outv)
{
  const float* trow = srt;
  const float* c0r = srt + NS;
  const float* c1r = srt + 2*NS;
  const float* c2r = srt + 3*NS;
  const float* sgr = srt + 4*NS;
  __shared__ float ts[1024];
  __shared__ float r0[16], r1[16], r2[16];
  const int tid = threadIdx.x;
  float sd[24], inc[24];
  float run = 0.f;
  int base = tid*24;
  float tprev = trow[base];
  #pragma unroll
  for (int j = 0; j < 24; ++j) {
    int i = base + j;
    float tnext = (i < NT-1) ? trow[i+1] : 0.f;
    float delta = (i == NT-1) ? LASTD : (tnext - tprev);
    sd[j] = delta * sgr[i];
    run += sd[j];
    inc[j] = run;
    tprev = tnext;
  }
  ts[tid] = run; __syncthreads();
  for (int off = 1; off < 1024; off <<= 1) {
    float x = (tid>=off) ? ts[tid-off] : 0.f;
    __syncthreads();
    ts[tid] += x;
    __syncthreads();
  }
  float excl = ts[tid] - run;
  float a0=0.f, a1=0.f, a2=0.f;
  #pragma unroll
  for (int j = 0; j < 24; ++j) {
    int i = base + j;
    float T = expf(-(excl+inc[j]));
    float w = T*(1.f-expf(-sd[j]));
    a0 += c0r[i]*w; a1 += c1r[i]*w; a2 += c2r[i]*w;
  }
  for (int off = 32; off; off >>= 1) {
    a0 += __shfl_down(a0, off); a1 += __shfl_down(a1, off); a2 += __shfl_down(a2, off);
  }
  int wid = tid>>6, lane = tid&63;
  if (lane==0) { r0[wid]=a0; r1[wid]=a1; r2[wid]=a2; }
  __syncthreads();
  if (tid==0) {
    float s0=0,s1=0,s2=0;
    for (int i=0;i<16;++i){s0+=r0[i];s1+=r1[i];s2+=r2[i];}
    outv[3]=s0; outv[4]=s1; outv[5]=s2;
  }
}

extern "C" void kernel_launch(void* const* d_in, const int* in_sizes, int n_in,
                              void* d_out, int out_size, void* d_ws, size_t ws_size,
                              hipStream_t stream) {
  (void)in_sizes; (void)n_in; (void)out_size; (void)ws_size;
  const float* hor  = (const float*)d_in[0];
  const float* ver  = (const float*)d_in[1];
  const float* tm   = (const float*)d_in[2];
  const float* nearp= (const float*)d_in[3];
  const float* farp = (const float*)d_in[4];
  const float* W0   = (const float*)d_in[5];
  const float* b0   = (const float*)d_in[6];
  const float* Wh   = (const float*)d_in[7];
  const float* bh   = (const float*)d_in[8];
  const float* Wsig = (const float*)d_in[9];
  const float* bsig = (const float*)d_in[10];
  const float* Wcol = (const float*)d_in[11];
  const float* bcol = (const float*)d_in[12];
  float* out = (float*)d_out;
  float* ws  = (float*)d_ws;

  float* cst   = ws + WS_CONST;
  float* tfine = ws + WS_TFINE;
  float* sigco = ws + WS_SIGCO;
  float* colco = ws + WS_COLCO;
  float* sigfi = ws + WS_SIGFI;
  float* colfi = ws + WS_COLFI;
  float* srt   = ws + WS_SORT;
  unsigned short* Wt = (unsigned short*)(ws + WS_WT);

  k_prep<<<dim3(1), dim3(64), 0, stream>>>(hor, ver, tm, nearp, farp, Wcol, bcol, cst);
  k_prep_w<<<dim3(528), dim3(256), 0, stream>>>(W0, Wh, Wt);
  k_mlp_mfma<<<dim3(NC/32), dim3(256), 0, stream>>>(cst, Wt, b0, bh, Wsig, bsig, Wcol,
                                                    (const float*)nullptr, NC, sigco, colco);
  k_postco<<<dim3(1), dim3(1024), 0, stream>>>(sigco, colco, cst, tfine, out);
  k_mlp_mfma<<<dim3(NF/32), dim3(256), 0, stream>>>(cst, Wt, b0, bh, Wsig, bsig, Wcol,
                                                    (const float*)tfine, NF, sigfi, colfi);
  k_fill<<<dim3(160), dim3(1024), 0, stream>>>(cst, sigco, colco, sigfi, colfi, tfine, srt);
  k_sort_local_full<<<dim3(80), dim3(1024), 0, stream>>>(srt);
  for (int k = 4096; k <= NS; k <<= 1) {
    for (int j = k>>1; j >= 2048; j >>= 1)
      k_sort_global<<<dim3(80), dim3(1024), 0, stream>>>(srt, k, j);
    k_sort_local_tail<<<dim3(80), dim3(1024), 0, stream>>>(srt, k);
  }
  k_final<<<dim3(1), dim3(1024), 0, stream>>>(srt, out);
}